// Round 5
// baseline (235.696 us; speedup 1.0000x reference)
//
#include <hip/hip_runtime.h>

// DAGConstraintLayer: out[b,i] = sigmoid(min over root-to-i chain of x[b,i]).
// R3 was latency-bound: serialized 15-deep ds_read->min->div->ds_write chain
// (VGPR=16, nothing hoisted), full fp division (no fast-math), and block-wide
// barrier/vmcnt drains. R4/R5: barrier-FREE — each wave owns 8 rows end-to-end:
// global_load_lds dwordx4 stage-in (no VGPR roundtrip), private vmcnt(0) wait,
// all LDS reads hoisted/batched, tree-min entirely in registers, sigmoid via
// raw v_exp_f32 + v_rcp_f32, batched writes, per-wave float4 stage-out.
// (R5 = R4 with clang-native vector type for __builtin_nontemporal_store.)

#define NODES 127
#define RPW   8                    // rows per wave
#define WPB   4                    // waves per block
#define RPB   (RPW * WPB)          // 32 rows per block
#define BLOCK 256
#define WF4   ((RPW * NODES) / 4)  // 254 float4 per wave (= 3*64 + 62)

typedef float v4 __attribute__((ext_vector_type(4)));   // clang-native 16B vector
typedef const __attribute__((address_space(1))) v4* gp4;
typedef __attribute__((address_space(3))) v4* lp4;

__device__ __forceinline__ float sigf(float v) {
    float e = __builtin_amdgcn_exp2f(v * -1.44269504089f);  // exp(-v)
    return __builtin_amdgcn_rcpf(1.0f + e);                 // raw v_rcp_f32: ~1ulp, threshold is 2e-2
}

__global__ __launch_bounds__(BLOCK) void dag_kernel(const float* __restrict__ x,
                                                    float* __restrict__ out) {
    __shared__ float buf[RPB * NODES];                 // 16,256 B
    v4* b4 = (v4*)buf;

    const int t    = threadIdx.x;
    const int lane = t & 63;
    const int w    = t >> 6;
    const size_t blk = (size_t)blockIdx.x * (RPB * NODES);
    const v4* src4 = (const v4*)(x + blk);             // 16B-aligned: 32*127*4 = 16256
    v4*       dst4 = (v4*)(out + blk);
    const int wf4 = w * WF4;

    // ---- stage-in: per-wave global->LDS DMA (dwordx4), lane-contiguous ----
    #pragma unroll
    for (int k = 0; k < 3; ++k) {
        int idx = wf4 + k * 64 + lane;
        __builtin_amdgcn_global_load_lds((gp4)(src4 + idx), (lp4)(b4 + idx), 16, 0, 0);
    }
    if (lane < 62) {
        int idx = wf4 + 192 + lane;
        __builtin_amdgcn_global_load_lds((gp4)(src4 + idx), (lp4)(b4 + idx), 16, 0, 0);
    }
    __builtin_amdgcn_s_waitcnt(0x0F70);   // vmcnt(0) only — this wave's DMA is done

    // ---- compute: 8 threads/row over this wave's 8 rows; reads hoisted ----
    const int r = lane >> 3;              // local row 0..7
    const int s = lane & 7;               // subtree 0..7 (root = 7+s)
    const int o = w * (RPW * NODES) + r * NODES;

    // top 7 nodes: same addr across a row's 8 lanes -> LDS broadcast, conflict-free
    float x0 = buf[o + 0], x1 = buf[o + 1], x2 = buf[o + 2], x3 = buf[o + 3];
    float x4 = buf[o + 4], x5 = buf[o + 5], x6 = buf[o + 6];
    // depth-3 subtree of thread s: 1 + 2 + 4 + 8 nodes
    float r3  = buf[o + 7 + s];
    float r40 = buf[o + 15 + 2 * s], r41 = buf[o + 16 + 2 * s];
    float r50 = buf[o + 31 + 4 * s], r51 = buf[o + 32 + 4 * s];
    float r52 = buf[o + 33 + 4 * s], r53 = buf[o + 34 + 4 * s];
    float r60 = buf[o + 63 + 8 * s], r61 = buf[o + 64 + 8 * s];
    float r62 = buf[o + 65 + 8 * s], r63 = buf[o + 66 + 8 * s];
    float r64 = buf[o + 67 + 8 * s], r65 = buf[o + 68 + 8 * s];
    float r66 = buf[o + 69 + 8 * s], r67 = buf[o + 70 + 8 * s];

    // path-mins of the top 3 levels (pure VALU)
    float p1 = fminf(x0, x1), p2 = fminf(x0, x2);
    float p3 = fminf(p1, x3), p4 = fminf(p1, x4);
    float p5 = fminf(p2, x5), p6 = fminf(p2, x6);

    // ancestor path-min of subtree root 7+s: parent is node 3+(s>>1)
    float pa = (s & 4) ? ((s & 2) ? p6 : p5) : ((s & 2) ? p4 : p3);

    float v3  = fminf(pa, r3);
    float v40 = fminf(v3, r40),  v41 = fminf(v3, r41);
    float v50 = fminf(v40, r50), v51 = fminf(v40, r51);
    float v52 = fminf(v41, r52), v53 = fminf(v41, r53);
    float v60 = fminf(v50, r60), v61 = fminf(v50, r61);
    float v62 = fminf(v51, r62), v63 = fminf(v51, r63);
    float v64 = fminf(v52, r64), v65 = fminf(v52, r65);
    float v66 = fminf(v53, r66), v67 = fminf(v53, r67);

    // ---- writes (batched; same wave => LDS pipe in-order vs reads above) ----
    buf[o + 7 + s]      = sigf(v3);
    buf[o + 15 + 2 * s] = sigf(v40);  buf[o + 16 + 2 * s] = sigf(v41);
    buf[o + 31 + 4 * s] = sigf(v50);  buf[o + 32 + 4 * s] = sigf(v51);
    buf[o + 33 + 4 * s] = sigf(v52);  buf[o + 34 + 4 * s] = sigf(v53);
    buf[o + 63 + 8 * s] = sigf(v60);  buf[o + 64 + 8 * s] = sigf(v61);
    buf[o + 65 + 8 * s] = sigf(v62);  buf[o + 66 + 8 * s] = sigf(v63);
    buf[o + 67 + 8 * s] = sigf(v64);  buf[o + 68 + 8 * s] = sigf(v65);
    buf[o + 69 + 8 * s] = sigf(v66);  buf[o + 70 + 8 * s] = sigf(v67);

    // top-7 nodes: lane s (<7) of each row writes node s; select its path-min
    float ta = (s & 1) ? ((s & 2) ? p3 : p1) : ((s & 2) ? p2 : x0);  // s in 0..3
    float tb = (s & 1) ? p5 : ((s & 2) ? p6 : p4);                   // s in 4..6
    float vt = (s & 4) ? tb : ta;
    if (s < 7) buf[o + s] = sigf(vt);

    // ---- stage-out: per-wave coalesced float4 (in-order LDS => sees writes) ----
    #pragma unroll
    for (int k = 0; k < 3; ++k) {
        int idx = wf4 + k * 64 + lane;
        __builtin_nontemporal_store(b4[idx], dst4 + idx);
    }
    if (lane < 62) {
        int idx = wf4 + 192 + lane;
        __builtin_nontemporal_store(b4[idx], dst4 + idx);
    }
}

extern "C" void kernel_launch(void* const* d_in, const int* in_sizes, int n_in,
                              void* d_out, int out_size, void* d_ws, size_t ws_size,
                              hipStream_t stream) {
    const float* x = (const float*)d_in[0];
    float* out = (float*)d_out;
    int rows = in_sizes[0] / NODES;        // 262144
    int grid = rows / RPB;                 // 8192 exactly
    dag_kernel<<<grid, BLOCK, 0, stream>>>(x, out);
}

// Round 6
// 230.790 us; speedup vs baseline: 1.0213x; 1.0213x over previous
//
#include <hip/hip_runtime.h>

// DAGConstraintLayer: out[b,i] = sigmoid(min over root-to-i chain of x[b,i]).
// R5 (one-shot blocks, vmcnt(0) stall) was latency/grain-bound: no pipe >40%,
// occupancy 65%, 8192 tiny blocks each serializing load-stall->compute->exit.
// R6: persistent waves (1024 blocks = 4/CU exactly), per-wave DOUBLE-BUFFERED
// pipeline over 8 tiles: issue global_load_lds for tile k+1, then wait
// vmcnt(4) (only tile k's loads — prior stores stay in flight; never vmcnt(0)
// in steady state), compute tile k, store tile k. HBM latency hides behind
// the previous tile's compute; zero barriers, zero block re-dispatch.

#define NODES 127
#define RPW   8                    // rows per wave-tile
#define WPB   4                    // waves per block
#define BLOCK 256
#define TPW   (RPW * NODES)        // 1016 floats per tile
#define TF4   (TPW / 4)            // 254 float4 per tile (= 3*64 + 62)
#define GRID  1024                 // persistent: 4 blocks/CU x 256 CU

typedef float v4 __attribute__((ext_vector_type(4)));
typedef const __attribute__((address_space(1))) v4* gp4;
typedef __attribute__((address_space(3))) v4* lp4;

__device__ __forceinline__ float sigf(float v) {
    float e = __builtin_amdgcn_exp2f(v * -1.44269504089f);  // exp(-v)
    return __builtin_amdgcn_rcpf(1.0f + e);                 // ~1ulp, threshold 2e-2
}

__device__ __forceinline__ void issue_loads(const v4* __restrict__ src4, int tf4,
                                            lp4 ldst, int lane) {
    #pragma unroll
    for (int k = 0; k < 3; ++k)
        __builtin_amdgcn_global_load_lds((gp4)(src4 + tf4 + k * 64 + lane),
                                         ldst + k * 64 + lane, 16, 0, 0);
    if (lane < 62)
        __builtin_amdgcn_global_load_lds((gp4)(src4 + tf4 + 192 + lane),
                                         ldst + 192 + lane, 16, 0, 0);
}

__global__ __launch_bounds__(BLOCK) void dag_kernel(const float* __restrict__ x,
                                                    float* __restrict__ out,
                                                    int ntiles) {
    __shared__ float buf[WPB][2][TPW];          // 32,512 B -> 4 blocks/CU
    const int t    = threadIdx.x;
    const int lane = t & 63;
    const int w    = t >> 6;
    const int wid  = blockIdx.x * WPB + w;
    const int nw   = GRID * WPB;                // 4096 waves total
    const int iters = ntiles / nw;              // 8 (exact)

    const v4* src4 = (const v4*)x;
    v4*       dst4 = (v4*)out;
    const int r = lane >> 3;                    // local row 0..7
    const int s = lane & 7;                     // subtree 0..7 (root 7+s)
    const int o = r * NODES;

    issue_loads(src4, wid * TF4, (lp4)&buf[w][0][0], lane);   // prefetch tile 0

    for (int it = 0; it < iters; ++it) {
        const int cur = it & 1;
        // queue (oldest->newest): [loads(it) x4, stores(it-1) x4]
        if (it == 0) __builtin_amdgcn_s_waitcnt(0x0F70);      // vmcnt(0)
        else         __builtin_amdgcn_s_waitcnt(0x0F74);      // vmcnt(4): loads(it) done
        if (it + 1 < iters)
            issue_loads(src4, (wid + (it + 1) * nw) * TF4, (lp4)&buf[w][cur ^ 1][0], lane);

        float* lb = &buf[w][cur][0];

        // ---- compute: 8 threads/row, reads hoisted; top-7 via LDS broadcast ----
        float x0 = lb[o + 0], x1 = lb[o + 1], x2 = lb[o + 2], x3 = lb[o + 3];
        float x4_ = lb[o + 4], x5 = lb[o + 5], x6 = lb[o + 6];
        float r3  = lb[o + 7 + s];
        float r40 = lb[o + 15 + 2 * s], r41 = lb[o + 16 + 2 * s];
        float r50 = lb[o + 31 + 4 * s], r51 = lb[o + 32 + 4 * s];
        float r52 = lb[o + 33 + 4 * s], r53 = lb[o + 34 + 4 * s];
        float r60 = lb[o + 63 + 8 * s], r61 = lb[o + 64 + 8 * s];
        float r62 = lb[o + 65 + 8 * s], r63 = lb[o + 66 + 8 * s];
        float r64 = lb[o + 67 + 8 * s], r65 = lb[o + 68 + 8 * s];
        float r66 = lb[o + 69 + 8 * s], r67 = lb[o + 70 + 8 * s];

        float p1 = fminf(x0, x1), p2 = fminf(x0, x2);
        float p3 = fminf(p1, x3), p4 = fminf(p1, x4_);
        float p5 = fminf(p2, x5), p6 = fminf(p2, x6);
        float pa = (s & 4) ? ((s & 2) ? p6 : p5) : ((s & 2) ? p4 : p3);

        float v3  = fminf(pa, r3);
        float v40 = fminf(v3, r40),  v41 = fminf(v3, r41);
        float v50 = fminf(v40, r50), v51 = fminf(v40, r51);
        float v52 = fminf(v41, r52), v53 = fminf(v41, r53);
        float v60 = fminf(v50, r60), v61 = fminf(v50, r61);
        float v62 = fminf(v51, r62), v63 = fminf(v51, r63);
        float v64 = fminf(v52, r64), v65 = fminf(v52, r65);
        float v66 = fminf(v53, r66), v67 = fminf(v53, r67);

        lb[o + 7 + s]      = sigf(v3);
        lb[o + 15 + 2 * s] = sigf(v40);  lb[o + 16 + 2 * s] = sigf(v41);
        lb[o + 31 + 4 * s] = sigf(v50);  lb[o + 32 + 4 * s] = sigf(v51);
        lb[o + 33 + 4 * s] = sigf(v52);  lb[o + 34 + 4 * s] = sigf(v53);
        lb[o + 63 + 8 * s] = sigf(v60);  lb[o + 64 + 8 * s] = sigf(v61);
        lb[o + 65 + 8 * s] = sigf(v62);  lb[o + 66 + 8 * s] = sigf(v63);
        lb[o + 67 + 8 * s] = sigf(v64);  lb[o + 68 + 8 * s] = sigf(v65);
        lb[o + 69 + 8 * s] = sigf(v66);  lb[o + 70 + 8 * s] = sigf(v67);

        float ta = (s & 1) ? ((s & 2) ? p3 : p1) : ((s & 2) ? p2 : x0);
        float tb = (s & 1) ? p5 : ((s & 2) ? p6 : p4);
        float vt = (s & 4) ? tb : ta;
        if (s < 7) lb[o + s] = sigf(vt);

        // ---- stage-out: coalesced float4 (same wave => LDS in-order) ----
        const int tb4 = (wid + it * nw) * TF4;
        v4* lb4 = (v4*)lb;
        #pragma unroll
        for (int k = 0; k < 3; ++k)
            dst4[tb4 + k * 64 + lane] = lb4[k * 64 + lane];
        if (lane < 62)
            dst4[tb4 + 192 + lane] = lb4[192 + lane];
    }
}

extern "C" void kernel_launch(void* const* d_in, const int* in_sizes, int n_in,
                              void* d_out, int out_size, void* d_ws, size_t ws_size,
                              hipStream_t stream) {
    const float* x = (const float*)d_in[0];
    float* out = (float*)d_out;
    int rows   = in_sizes[0] / NODES;      // 262144
    int ntiles = rows / RPW;               // 32768
    dag_kernel<<<GRID, BLOCK, 0, stream>>>(x, out, ntiles);
}